// Round 6
// baseline (724.293 us; speedup 1.0000x reference)
//
#include <hip/hip_runtime.h>
#include <hip/hip_bf16.h>

// ---------------------------------------------------------------------------
// MoE layer: router (softmax, top-2) + 16 experts (D=2048 -> H=1024 -> D) +
// shared expert (D -> F=1024 -> D), gate-weighted combine, aux stats.
// R5: (a) shared expert folded in as group 16 -> TWO grouped GEMMs total;
//     (b) 256x256xBK64 8-phase schedule (T3+T4 counted vmcnt, T2 XOR swizzle,
//         T5 setprio), 8 waves / 512 threads, 128 KiB LDS, per-K-tile dbuf.
// ---------------------------------------------------------------------------

#define N_TOK 8192
#define DDIM  2048
#define NEXP  16
#define HDIM  1024
#define FDIM  1024
#define NASSIGN (N_TOK * 2)
#define NROWS (NASSIGN + N_TOK)      // 24576: expert assignments + shared rows

typedef __attribute__((ext_vector_type(8))) short bf16x8;
typedef __attribute__((ext_vector_type(4))) float f32x4;
typedef __attribute__((ext_vector_type(8))) unsigned short u16x8;
typedef __attribute__((ext_vector_type(4))) unsigned short u16x4;

__device__ inline unsigned short f2bf(float f) {
    unsigned int u = __builtin_bit_cast(unsigned int, f);
    u += 0x7FFFu + ((u >> 16) & 1u);           // RNE (finite inputs only)
    return (unsigned short)(u >> 16);
}

__device__ inline float bf2f(unsigned short h) {
    return __builtin_bit_cast(float, (unsigned int)h << 16);
}

__device__ inline float gelu_f(float v) {
    return 0.5f * v * (1.0f + erff(v * 0.7071067811865475f));
}

__device__ inline void gld16(void* lds, const void* g) {
    __builtin_amdgcn_global_load_lds(
        (const __attribute__((address_space(1))) unsigned int*)g,
        (__attribute__((address_space(3))) unsigned int*)lds, 16, 0, 0);
}

// ---------------------------------------------------------------------------
__global__ __launch_bounds__(256) void zero_small(float* imp) {
    if (threadIdx.x < NEXP) imp[threadIdx.x] = 0.0f;
}

// x fp32 -> bf16, 8 elems/thread
__global__ __launch_bounds__(256) void cast_x_kernel(const float* __restrict__ x,
                                                     unsigned short* __restrict__ xb) {
    size_t i = (size_t)blockIdx.x * 256 + threadIdx.x;   // group of 8
    const float4 a = ((const float4*)x)[i * 2];
    const float4 b = ((const float4*)x)[i * 2 + 1];
    u16x8 o;
    o[0] = f2bf(a.x); o[1] = f2bf(a.y); o[2] = f2bf(a.z); o[3] = f2bf(a.w);
    o[4] = f2bf(b.x); o[5] = f2bf(b.y); o[6] = f2bf(b.z); o[7] = f2bf(b.w);
    *(u16x8*)(xb + i * 8) = o;
}

// [R][C] fp32 -> [C][R] bf16, 64x64 LDS tiles, batched over blockIdx.z
template <int R, int C>
__global__ __launch_bounds__(256) void transpose_cast(const float* __restrict__ src,
                                                      unsigned short* __restrict__ dst) {
    __shared__ unsigned short t[64][66];
    const size_t zoff = (size_t)blockIdx.z * R * C;
    src += zoff; dst += zoff;
    const int r0 = blockIdx.y * 64, c0 = blockIdx.x * 64;
    const int tid = threadIdx.x;
    const int cr = tid >> 4;            // 0..15
    const int cc4 = (tid & 15) * 4;
#pragma unroll
    for (int it = 0; it < 4; ++it) {
        int row = cr + it * 16;
        const float4 v = *(const float4*)(src + (size_t)(r0 + row) * C + c0 + cc4);
        t[row][cc4 + 0] = f2bf(v.x); t[row][cc4 + 1] = f2bf(v.y);
        t[row][cc4 + 2] = f2bf(v.z); t[row][cc4 + 3] = f2bf(v.w);
    }
    __syncthreads();
#pragma unroll
    for (int it = 0; it < 4; ++it) {
        int cc = cr + it * 16;
        u16x4 o;
#pragma unroll
        for (int j = 0; j < 4; ++j) o[j] = t[cc4 + j][cc];
        *(u16x4*)(dst + (size_t)(c0 + cc) * R + r0 + cc4) = o;
    }
}

// ---------------------------------------------------------------------------
// Router: one wave per token. logits = x@Wr (16), gate = x@Wg; softmax; top-2.
__global__ __launch_bounds__(256) void router_kernel(
    const float* __restrict__ x, const float* __restrict__ Wr, const float* __restrict__ Wg,
    float* __restrict__ gsh, int* __restrict__ t2i, float* __restrict__ t2v,
    float* __restrict__ imp) {
    __shared__ float simp[NEXP];
    const int tid = threadIdx.x, lane = tid & 63, w = tid >> 6;
    if (tid < NEXP) simp[tid] = 0.0f;
    __syncthreads();
    const int n = blockIdx.x * 4 + w;
    const float* xr = x + (size_t)n * DDIM;
    float acc[NEXP];
#pragma unroll
    for (int e = 0; e < NEXP; ++e) acc[e] = 0.0f;
    float ag = 0.0f;
    for (int j = 0; j < DDIM / 64; ++j) {
        int d = lane + j * 64;
        float xv = xr[d];
        const float* wr = Wr + (size_t)d * NEXP;
#pragma unroll
        for (int e = 0; e < NEXP; ++e) acc[e] = fmaf(xv, wr[e], acc[e]);
        ag = fmaf(xv, Wg[d], ag);
    }
#pragma unroll
    for (int off = 32; off; off >>= 1) {
#pragma unroll
        for (int e = 0; e < NEXP; ++e) acc[e] += __shfl_xor(acc[e], off);
        ag += __shfl_xor(ag, off);
    }
    if (lane == 0) {
        float mx = acc[0];
#pragma unroll
        for (int e = 1; e < NEXP; ++e) mx = fmaxf(mx, acc[e]);
        float p[NEXP], s = 0.0f;
#pragma unroll
        for (int e = 0; e < NEXP; ++e) { p[e] = expf(acc[e] - mx); s += p[e]; }
        const float inv = 1.0f / s;
        int i1 = 0; float v1 = -1.0f;
#pragma unroll
        for (int e = 0; e < NEXP; ++e) {
            p[e] *= inv;
            if (p[e] > v1) { v1 = p[e]; i1 = e; }
        }
        int i2 = 0; float v2 = -1.0f;
#pragma unroll
        for (int e = 0; e < NEXP; ++e) {
            if (e != i1 && p[e] > v2) { v2 = p[e]; i2 = e; }
        }
        t2i[2 * n] = i1; t2i[2 * n + 1] = i2;
        t2v[2 * n] = v1; t2v[2 * n + 1] = v2;
        gsh[n] = 1.0f / (1.0f + expf(-ag));
#pragma unroll
        for (int e = 0; e < NEXP; ++e) atomicAdd(&simp[e], p[e]);
    }
    __syncthreads();
    if (tid < NEXP) unsafeAtomicAdd(&imp[tid], simp[tid]);
}

// Single block: histogram counts, exclusive scan -> offsets, aux outputs, fill=0
__global__ __launch_bounds__(256) void scan_finalize(
    const int* __restrict__ t2i, const float* __restrict__ imp,
    int* __restrict__ offs, int* __restrict__ fill, float* __restrict__ out_tail) {
    __shared__ int hist[NEXP];
    const int tid = threadIdx.x;
    if (tid < NEXP) hist[tid] = 0;
    __syncthreads();
    for (int i = tid; i < NASSIGN; i += 256) atomicAdd(&hist[t2i[i]], 1);
    __syncthreads();
    if (tid == 0) {
        int o = 0;
        for (int e = 0; e < NEXP; ++e) { offs[e] = o; o += hist[e]; }
        offs[NEXP] = o;              // = NASSIGN
        offs[NEXP + 1] = NROWS;      // shared-expert group (group 16)
    }
    if (tid < NEXP) {
        fill[tid] = 0;
        out_tail[tid] = imp[tid] * (1.0f / (float)N_TOK);
        out_tail[NEXP + tid] = (float)hist[tid] / (float)NASSIGN;
    }
}

// also records t2pos (token,k)->slot, and fills the shared-group tail rows
__global__ __launch_bounds__(256) void build_assign(
    const int* __restrict__ t2i, const float* __restrict__ t2v,
    const int* __restrict__ offs, int* __restrict__ fill,
    int* __restrict__ atok, float* __restrict__ agate, int* __restrict__ t2pos) {
    const int n = blockIdx.x * 256 + threadIdx.x;
#pragma unroll
    for (int k = 0; k < 2; ++k) {
        int e = t2i[2 * n + k];
        int pos = offs[e] + atomicAdd(&fill[e], 1);
        atok[pos] = n;
        agate[pos] = t2v[2 * n + k];
        t2pos[2 * n + k] = pos;
    }
    atok[NASSIGN + n] = n;           // shared group: identity gather
    agate[NASSIGN + n] = 1.0f;       // gsh applied in combine
}

// y[n][d] = contrib[p0][d] + contrib[p1][d] + gsh[n]*contrib[shared(n)][d]
__global__ __launch_bounds__(256) void combine_kernel(
    const unsigned short* __restrict__ contrib, const int* __restrict__ t2pos,
    const float* __restrict__ gsh, float* __restrict__ y) {
    const int gi = blockIdx.x * 256 + threadIdx.x;      // group of 8 floats
    const int n = gi >> 8;                              // DDIM/8 = 256 groups/row
    const int d8 = (gi & 255) * 8;
    const int p0 = t2pos[2 * n], p1 = t2pos[2 * n + 1];
    const float g = gsh[n];
    u16x8 a = *(const u16x8*)(contrib + (size_t)p0 * DDIM + d8);
    u16x8 b = *(const u16x8*)(contrib + (size_t)p1 * DDIM + d8);
    u16x8 c = *(const u16x8*)(contrib + (size_t)(NASSIGN + n) * DDIM + d8);
    float4 y0, y1;
    y0.x = bf2f(a[0]) + bf2f(b[0]) + g * bf2f(c[0]);
    y0.y = bf2f(a[1]) + bf2f(b[1]) + g * bf2f(c[1]);
    y0.z = bf2f(a[2]) + bf2f(b[2]) + g * bf2f(c[2]);
    y0.w = bf2f(a[3]) + bf2f(b[3]) + g * bf2f(c[3]);
    y1.x = bf2f(a[4]) + bf2f(b[4]) + g * bf2f(c[4]);
    y1.y = bf2f(a[5]) + bf2f(b[5]) + g * bf2f(c[5]);
    y1.z = bf2f(a[6]) + bf2f(b[6]) + g * bf2f(c[6]);
    y1.w = bf2f(a[7]) + bf2f(b[7]) + g * bf2f(c[7]);
    float* yr = y + (size_t)n * DDIM + d8;
    *(float4*)yr = y0;
    *(float4*)(yr + 4) = y1;
}

// ---------------------------------------------------------------------------
// Grouped GEMM, 256x256 tile, BK=64, 8 waves (2Mx4N), 8-phase schedule.
// C[M][NC] = A[M][KD] * B^T[NC][KD], bf16 in, fp32 accum.
// MODE 0: L1 (A = gathered xb, out = f2bf(gelu(v)*gate) -> hb[NROWS][HDIM])
// MODE 1: L2 (A = hb rows,     out = f2bf(v)            -> contrib[NROWS][DDIM])
//
// LDS: per K-tile double buffer d = t&1. Half-tile = 128 rows x 64 k (16 KiB).
// Swizzle (both-sides, rule #21): 16B slot s of row r holds k-chunk s^(r&7);
// staged via pre-swizzled GLOBAL source, read at slot (kh*4+q)^(c16&7).
// Schedule per K-tile t (phases p0..p3, quadrants of the 128x64 wave tile):
//   p0: ds A(mi0-3) + B(ni0-1); stage A-h0(t+1)->d^1 | bar; lgkm0; 16 MFMA; bar
//   p1: ds B(ni2-3);            stage A-h1(t+1)->d^1 | bar; lgkm0; 16 MFMA; bar
//   p2: ds A(mi4-7);            stage B-h0(t+2)->d   | bar; lgkm0; 16 MFMA; bar
//   p3:                         stage B-h1(t+2)->d   | bar;        16 MFMA;
//                                                      vmcnt(4); bar
// WAR safety: B[d] regions freed after p1-bar2 (staged p2/p3); A[d^1] freed
// after previous tile's p2-bar2 (staged p0/p1). vmcnt(4): the 4 loads issued
// after the newest half-tile needed by tile t+1 are exactly p2+p3's B stages.
// ---------------------------------------------------------------------------
#define BAR()   __builtin_amdgcn_s_barrier()
#define WAITL() do { asm volatile("s_waitcnt lgkmcnt(0)" ::: "memory"); \
                     __builtin_amdgcn_sched_barrier(0); } while (0)

#define RD_A(dst, mb) do {                                                  \
  _Pragma("unroll") for (int i_ = 0; i_ < 4; ++i_)                          \
  _Pragma("unroll") for (int kh_ = 0; kh_ < 2; ++kh_)                       \
    (dst)[i_][kh_] = *(const bf16x8*)(aB + rbA[kh_] + ((mb) + i_) * 2048);  \
} while (0)

#define RD_B(dst, nb) do {                                                  \
  _Pragma("unroll") for (int i_ = 0; i_ < 2; ++i_)                          \
  _Pragma("unroll") for (int kh_ = 0; kh_ < 2; ++kh_)                       \
    (dst)[i_][kh_] = *(const bf16x8*)(bB + rbB[kh_] + ((nb) + i_) * 2048);  \
} while (0)

#define MM(mb, nb, a_, b_) do {                                             \
  __builtin_amdgcn_s_setprio(1);                                            \
  _Pragma("unroll") for (int i_ = 0; i_ < 4; ++i_)                          \
  _Pragma("unroll") for (int n_ = 0; n_ < 2; ++n_)                          \
  _Pragma("unroll") for (int kh_ = 0; kh_ < 2; ++kh_)                       \
    acc[(mb) + i_][(nb) + n_] = __builtin_amdgcn_mfma_f32_16x16x32_bf16(    \
        (a_)[i_][kh_], (b_)[n_][kh_], acc[(mb) + i_][(nb) + n_], 0, 0, 0);  \
  __builtin_amdgcn_s_setprio(0);                                            \
} while (0)

#define STG(dstbuf, src, kt) do {                                           \
    gld16((char*)(dstbuf) + ldso0, (src)[0] + (size_t)(kt) * 64);           \
    gld16((char*)(dstbuf) + ldso1, (src)[1] + (size_t)(kt) * 64);           \
} while (0)

#define KTILE(d, t) do {                                                    \
    const char* aB = (const char*)As_[d][wm];                               \
    const char* bB = (const char*)Bs_[d][bh];                               \
    const int ka = ((t) + 1 < NT) ? (t) + 1 : (t);                          \
    const int kb = ((t) + 2 < NT) ? (t) + 2 : (t);                          \
    bf16x8 av[4][2], bv0[2][2], bv1[2][2];                                  \
    RD_A(av, 0); RD_B(bv0, 0);                                              \
    STG(As_[(d) ^ 1][0], sA[0], ka);                                        \
    BAR(); WAITL();                                                         \
    MM(0, 0, av, bv0);                                                      \
    BAR();                                                                  \
    RD_B(bv1, 2);                                                           \
    STG(As_[(d) ^ 1][1], sA[1], ka);                                        \
    BAR(); WAITL();                                                         \
    MM(0, 2, av, bv1);                                                      \
    BAR();                                                                  \
    RD_A(av, 4);                                                            \
    STG(Bs_[d][0], sB[0], kb);                                              \
    BAR(); WAITL();                                                         \
    MM(4, 0, av, bv0);                                                      \
    BAR();                                                                  \
    STG(Bs_[d][1], sB[1], kb);                                              \
    BAR();                                                                  \
    MM(4, 2, av, bv1);                                                      \
    asm volatile("s_waitcnt vmcnt(4)" ::: "memory");                        \
    BAR();                                                                  \
} while (0)

template <int MODE>
__global__ __launch_bounds__(512, 2) void gemm8(
    const unsigned short* __restrict__ A, const unsigned short* __restrict__ B,
    unsigned short* __restrict__ out,
    const int* __restrict__ offs, const int* __restrict__ atok,
    const float* __restrict__ agate) {
    constexpr int KD = MODE == 0 ? DDIM : HDIM;
    constexpr int NC = MODE == 0 ? HDIM : DDIM;
    constexpr int NT = KD / 64;
    const int e = blockIdx.z;
    const int m0 = offs[e];
    const int mE = offs[e + 1] - m0;
    const int tm = blockIdx.y;
    if (tm * 256 >= mE) return;
    const int n0 = blockIdx.x * 256;

    __shared__ __align__(16) unsigned short As_[2][2][128 * 64];   // 64 KiB
    __shared__ __align__(16) unsigned short Bs_[2][2][128 * 64];   // 64 KiB

    const int tid = threadIdx.x;
    const int lane = tid & 63, w = tid >> 6;       // wave 0..7
    const int wm = w >> 2, wn = w & 3;             // 2M x 4N wave grid
    const int bh = wn >> 1;

    // ---- staging descriptors (pre-swizzled global sources) ----
    const int kch = ((lane & 7) ^ ((lane >> 3) & 7)) * 8;   // element offset
    const int ldso0 = (w * 128 + lane) * 16;
    const int ldso1 = (w * 128 + 64 + lane) * 16;
    const unsigned short* sA[2][2];
    const unsigned short* sB[2][2];
#pragma unroll
    for (int h = 0; h < 2; ++h) {
#pragma unroll
        for (int j = 0; j < 2; ++j) {
            int rr = h * 128 + w * 16 + j * 8 + (lane >> 3);   // row in tile
            int ar = tm * 256 + rr; ar = ar < mE ? ar : mE - 1;
            if (MODE == 0)
                sA[h][j] = A + (size_t)atok[m0 + ar] * KD + kch;
            else
                sA[h][j] = A + (size_t)(m0 + ar) * KD + kch;
            sB[h][j] = B + (size_t)e * KD * NC + (size_t)(n0 + rr) * KD + kch;
        }
    }

    // ---- fragment read bases (swizzled) ----
    const int c16 = lane & 15, q = lane >> 4;
    int rbA[2], rbB[2];
#pragma unroll
    for (int kh = 0; kh < 2; ++kh) {
        int sl = (kh * 4 + q) ^ (c16 & 7);
        rbA[kh] = c16 * 128 + sl * 16;
        rbB[kh] = ((wn & 1) * 64 + c16) * 128 + sl * 16;
    }

    f32x4 acc[8][4];
#pragma unroll
    for (int i = 0; i < 8; ++i)
#pragma unroll
        for (int j = 0; j < 4; ++j) acc[i][j] = (f32x4){0.f, 0.f, 0.f, 0.f};

    // prologue: K-tile0 A+B -> dbuf0; K-tile1 B -> dbuf1 (A(1) staged in Kt0)
    STG(As_[0][0], sA[0], 0); STG(As_[0][1], sA[1], 0);
    STG(Bs_[0][0], sB[0], 0); STG(Bs_[0][1], sB[1], 0);
    STG(Bs_[1][0], sB[0], 1); STG(Bs_[1][1], sB[1], 1);
    asm volatile("s_waitcnt vmcnt(4)" ::: "memory");
    BAR();

#pragma unroll 1
    for (int it = 0; it < NT / 2; ++it) {
        const int t0 = it * 2;
        KTILE(0, t0);
        KTILE(1, t0 + 1);
    }

    // epilogue: C/D layout col = lane&15, row = (lane>>4)*4 + reg
    const int col = lane & 15, r4 = (lane >> 4) * 4;
#pragma unroll
    for (int mi = 0; mi < 8; ++mi) {
#pragma unroll
        for (int r = 0; r < 4; ++r) {
            int grow = tm * 256 + wm * 128 + mi * 16 + r4 + r;
            if (grow >= mE) continue;
            float gate = (MODE == 0) ? agate[m0 + grow] : 0.0f;
#pragma unroll
            for (int ni = 0; ni < 4; ++ni) {
                int gcol = n0 + wn * 64 + ni * 16 + col;
                float v = acc[mi][ni][r];
                if (MODE == 0)
                    out[(size_t)(m0 + grow) * NC + gcol] = f2bf(gelu_f(v) * gate);
                else
                    out[(size_t)(m0 + grow) * NC + gcol] = f2bf(v);
            }
        }
    }
}

// ---------------------------------------------------------------------------
extern "C" void kernel_launch(void* const* d_in, const int* in_sizes, int n_in,
                              void* d_out, int out_size, void* d_ws, size_t ws_size,
                              hipStream_t stream) {
    const float* x   = (const float*)d_in[0];
    const float* Wr  = (const float*)d_in[1];
    const float* Wg  = (const float*)d_in[2];
    const float* W1  = (const float*)d_in[3];
    const float* W2  = (const float*)d_in[4];
    const float* W1s = (const float*)d_in[5];
    const float* W2s = (const float*)d_in[6];
    float* out = (float*)d_out;

    char* ws = (char*)d_ws;
    size_t off = 0;
    auto carve = [&](size_t bytes) { char* p = ws + off; off += (bytes + 255) & ~(size_t)255; return p; };
    // NOTE: contrib (NROWS x DDIM bf16 = 96 MiB) aliases [xb, w1all] (100 MiB),
    // both dead after gemm8<0>; stream order serializes the reuse.
    unsigned short* xb    = (unsigned short*)carve((size_t)N_TOK * DDIM * 2);            // 32 MiB
    unsigned short* w1all = (unsigned short*)carve((size_t)(NEXP + 1) * DDIM * HDIM * 2);// 68 MiB
    unsigned short* w2all = (unsigned short*)carve((size_t)(NEXP + 1) * HDIM * DDIM * 2);// 68 MiB
    unsigned short* hb    = (unsigned short*)carve((size_t)NROWS * HDIM * 2);            // 48 MiB
    float* gsh            = (float*)carve((size_t)N_TOK * 4);
    int* t2i              = (int*)carve((size_t)N_TOK * 2 * 4);
    float* t2v            = (float*)carve((size_t)N_TOK * 2 * 4);
    int* atok             = (int*)carve((size_t)NROWS * 4);
    float* agate          = (float*)carve((size_t)NROWS * 4);
    int* t2pos            = (int*)carve((size_t)NASSIGN * 4);
    float* imp            = (float*)carve(256);
    int* offs             = (int*)carve(256);
    int* fill             = (int*)carve(256);
    if (ws_size < off) return;   // fail loudly (output stays invalid)

    unsigned short* contrib = (unsigned short*)ws;   // alias over xb+w1all

    float* out_tail = out + (size_t)N_TOK * DDIM;

    hipLaunchKernelGGL(zero_small, dim3(1), dim3(256), 0, stream, imp);
    hipLaunchKernelGGL(cast_x_kernel, dim3(N_TOK * DDIM / 8 / 256), dim3(256), 0, stream, x, xb);
    // weights, transposed to B^T[NC][KD], shared expert appended as group 16
    hipLaunchKernelGGL((transpose_cast<DDIM, HDIM>), dim3(HDIM / 64, DDIM / 64, NEXP), dim3(256), 0, stream, W1, w1all);
    hipLaunchKernelGGL((transpose_cast<DDIM, HDIM>), dim3(HDIM / 64, DDIM / 64, 1), dim3(256), 0, stream,
                       W1s, w1all + (size_t)NEXP * DDIM * HDIM);
    hipLaunchKernelGGL((transpose_cast<HDIM, DDIM>), dim3(DDIM / 64, HDIM / 64, NEXP), dim3(256), 0, stream, W2, w2all);
    hipLaunchKernelGGL((transpose_cast<HDIM, DDIM>), dim3(DDIM / 64, HDIM / 64, 1), dim3(256), 0, stream,
                       W2s, w2all + (size_t)NEXP * HDIM * DDIM);
    hipLaunchKernelGGL(router_kernel, dim3(N_TOK / 4), dim3(256), 0, stream, x, Wr, Wg, gsh, t2i, t2v, imp);
    hipLaunchKernelGGL(scan_finalize, dim3(1), dim3(256), 0, stream, t2i, imp, offs, fill, out_tail);
    hipLaunchKernelGGL(build_assign, dim3(N_TOK / 256), dim3(256), 0, stream, t2i, t2v, offs, fill, atok, agate, t2pos);

    // grouped L1 (17 groups incl. shared): xb -> hb
    hipLaunchKernelGGL((gemm8<0>), dim3(HDIM / 256, N_TOK / 256, NEXP + 1), dim3(512), 0, stream,
                       xb, w1all, hb, offs, atok, agate);
    // grouped L2: hb -> contrib (overwrites xb/w1all region)
    hipLaunchKernelGGL((gemm8<1>), dim3(DDIM / 256, N_TOK / 256, NEXP + 1), dim3(512), 0, stream,
                       hb, w2all, contrib, offs, atok, agate);
    // y[n] = contrib[p0] + contrib[p1] + gsh*contrib[shared]
    hipLaunchKernelGGL(combine_kernel, dim3(N_TOK * DDIM / 8 / 256), dim3(256), 0, stream,
                       contrib, t2pos, gsh, out);
}